// Round 6
// baseline (714.447 us; speedup 1.0000x reference)
//
#include <hip/hip_runtime.h>
#include <cstdint>
#include <math.h>

typedef __bf16 bf16_t;
typedef __bf16 bf16x8 __attribute__((ext_vector_type(8)));
typedef __bf16 bf16x4 __attribute__((ext_vector_type(4)));
typedef float f32x4 __attribute__((ext_vector_type(4)));

#define MFMA16(a, b, c) __builtin_amdgcn_mfma_f32_16x16x32_bf16((a), (b), (c), 0, 0, 0)

static constexpr int BATCH = 4;
static constexpr int SEQ = 2048;
static constexpr int DIMC = 1024;
static constexpr int NH = 16;
static constexpr int HD = 64;

__device__ __forceinline__ void async_copy16(void* lds, const void* g) {
    __builtin_amdgcn_global_load_lds(
        (const __attribute__((address_space(1))) void*)g,
        (__attribute__((address_space(3))) void*)lds, 16, 0, 0);
}

__device__ __forceinline__ float fast_exp2(float x) {
#if __has_builtin(__builtin_amdgcn_exp2f)
    return __builtin_amdgcn_exp2f(x);
#else
    return __expf(x * 0.6931471805599453f);
#endif
}

// ---------------- fused prep: weight transpose+cvt | rope tables | input cvt ----------
// flat grid: [0,4096) = 4 weight transposes; [4096,4352) = rope; [4352,16640) = cvt3
__global__ __launch_bounds__(256) void prep(const float* __restrict__ Wq,
                                            const float* __restrict__ Wk,
                                            const float* __restrict__ Wv,
                                            const float* __restrict__ Wo,
                                            const float* __restrict__ q,
                                            const float* __restrict__ k,
                                            const float* __restrict__ v,
                                            bf16_t* __restrict__ WT,
                                            float* __restrict__ cosT,
                                            float* __restrict__ sinT,
                                            bf16_t* __restrict__ Cb) {
    __shared__ float tile[32][33];
    const int n = blockIdx.x;
    const int tid = threadIdx.x;
    if (n < 4096) {  // weight transpose + cvt: W fp32 [k][n] -> Wt bf16 [n][k]
        const int z = n >> 10;
        const int yx = n & 1023;
        const int by = yx >> 5, bx = yx & 31;
        const float* Ws[4] = {Wq, Wk, Wv, Wo};
        const float* W = Ws[z];
        bf16_t* Wt = WT + (size_t)z * DIMC * DIMC;
        const int tx = tid & 31;
        const int ty = tid >> 5;
        const int x0 = bx * 32;
        const int y0 = by * 32;
        #pragma unroll
        for (int jj = ty; jj < 32; jj += 8)
            tile[jj][tx] = W[(size_t)(y0 + jj) * DIMC + x0 + tx];
        __syncthreads();
        #pragma unroll
        for (int jj = ty; jj < 32; jj += 8)
            Wt[(size_t)(x0 + jj) * DIMC + y0 + tx] = (bf16_t)tile[tx][jj];
    } else if (n < 4352) {  // rope tables
        const int idx = (n - 4096) * 256 + tid;  // 65536 = 2048*32
        const int t = idx >> 5;
        const int p = idx & 31;
        const float inv = exp2f(-0.41524101186092029f * (float)p);
        const float ang = (float)t * inv;
        float s, c;
        sincosf(ang, &s, &c);
        cosT[idx] = c;
        sinT[idx] = s;
    } else {  // fp32 -> bf16 convert, 3 tensors
        const int m = n - 4352;
        const int y = m >> 12;
        const int x = m & 4095;
        const float* in = (y == 0) ? q : ((y == 1) ? k : v);
        bf16_t* o = Cb + (size_t)y * BATCH * SEQ * DIMC;
        const int i = x * 256 + tid;  // 8 elems per thread
        const float4 f0 = ((const float4*)in)[i * 2];
        const float4 f1 = ((const float4*)in)[i * 2 + 1];
        bf16x8 vv;
        vv[0] = (bf16_t)f0.x; vv[1] = (bf16_t)f0.y; vv[2] = (bf16_t)f0.z; vv[3] = (bf16_t)f0.w;
        vv[4] = (bf16_t)f1.x; vv[5] = (bf16_t)f1.y; vv[6] = (bf16_t)f1.z; vv[7] = (bf16_t)f1.w;
        ((bf16x8*)o)[i] = vv;
    }
}

// ===== shared GEMM k-loop body (128x128 tile, BK=32, swizzled LDS) =====
// As/Bs layout: element (row r in [0,128), k-granule g in [0,4)) at
//   r*32 + ((g ^ f(r)) << 3), f(r) = (r&3)^((r>>2)&3).  <=2-way bank aliasing.
#define GEMM_KLOOP(A_, Bt_)                                                             \
    f32x4 acc[4][4] = {};                                                               \
    const int swW = ((lane >> 2) & 3) ^ ((lane >> 4) & 3); /* write-side f(r) */        \
    const int rIn = lane >> 2;                             /* row within chunk */       \
    const int gW = ((lane & 3) ^ swW) * 8;                 /* logical k offset */       \
    const int fR = (l15 & 3) ^ ((l15 >> 2) & 3);           /* read-side f(r) */         \
    for (int kt = 0; kt < DIMC / 32; ++kt) {                                            \
        const int k0 = kt * 32;                                                         \
        __syncthreads();                                                                \
        _Pragma("unroll") for (int ci = 0; ci < 2; ++ci) {                              \
            const int c = 2 * w + ci;                                                   \
            async_copy16(&Bs[c * 512], Bt_ + (size_t)(col0 + c * 16 + rIn) * DIMC + k0 + gW); \
            async_copy16(&As[c * 512], A_ + (size_t)(row0 + c * 16 + rIn) * DIMC + k0 + gW);  \
        }                                                                               \
        __syncthreads();                                                                \
        bf16x8 af[4], bfr[4];                                                           \
        _Pragma("unroll") for (int mt = 0; mt < 4; ++mt)                                \
            af[mt] = *(const bf16x8*)&As[(wr * 64 + mt * 16 + l15) * 32 + ((quad ^ fR) << 3)]; \
        _Pragma("unroll") for (int nt = 0; nt < 4; ++nt)                                \
            bfr[nt] = *(const bf16x8*)&Bs[(wc * 64 + nt * 16 + l15) * 32 + ((quad ^ fR) << 3)]; \
        _Pragma("unroll") for (int mt = 0; mt < 4; ++mt)                                \
            _Pragma("unroll") for (int nt = 0; nt < 4; ++nt)                            \
                acc[mt][nt] = MFMA16(af[mt], bfr[nt], acc[mt][nt]);                     \
    }

// ---------------- fused QKV GEMM: z selects (A, W, bias, out) -----------------
// XCD swizzle: raw -> (row=raw%64, col=raw/64) so dispatch%8 = row%8.
// launch_bounds(256,6): cap VGPR<=85 so all 1536 blocks are co-resident (6/CU).
__global__ __launch_bounds__(256, 6) void gemm_qkv(const bf16_t* __restrict__ Cb,
                                                   const bf16_t* __restrict__ Wt3,
                                                   const float* __restrict__ bq,
                                                   const float* __restrict__ bk,
                                                   const float* __restrict__ bv,
                                                   bf16_t* __restrict__ Qr,
                                                   bf16_t* __restrict__ Kr,
                                                   bf16_t* __restrict__ Vr,
                                                   const float* __restrict__ cosT,
                                                   const float* __restrict__ sinT) {
    __shared__ __align__(16) unsigned char smem[32 * 132 * 4];  // 16.9 KB
    bf16_t* As = (bf16_t*)smem;
    bf16_t* Bs = (bf16_t*)(smem + 8192);
    float* eps = (float*)smem;
    const int z = blockIdx.z;
    const bf16_t* A = Cb + (size_t)z * BATCH * SEQ * DIMC;
    const bf16_t* Bt = Wt3 + (size_t)z * DIMC * DIMC;
    const float* bias = (z == 0) ? bq : ((z == 1) ? bk : bv);
    bf16_t* outp = (z == 0) ? Qr : ((z == 1) ? Kr : Vr);
    const bool rope = (z < 2);
    const int tid = threadIdx.x;
    const int w = tid >> 6;
    const int lane = tid & 63;
    const int l15 = lane & 15;
    const int quad = lane >> 4;
    const int wr = w >> 1, wc = w & 1;
    const int raw = blockIdx.y * 8 + blockIdx.x;
    const int row0 = (raw & 63) * 128, col0 = (raw >> 6) * 128;
    GEMM_KLOOP(A, Bt)
    float bvl[4];
    #pragma unroll
    for (int nt = 0; nt < 4; ++nt) bvl[nt] = bias[col0 + wc * 64 + nt * 16 + l15];
    const int lr = tid >> 3;  // 0..31 local row
    const int cg = tid & 7;   // 0..7 col group of 16
    const int c0 = cg * 16;
    const int h = (col0 + c0) >> 6;
    const int dbase = (col0 + c0) & 63;
    #pragma unroll
    for (int p = 0; p < 4; ++p) {  // p = mt slab (32 rows: wr0 & wr1)
        __syncthreads();
        #pragma unroll
        for (int nt = 0; nt < 4; ++nt)
            #pragma unroll
            for (int r = 0; r < 4; ++r)
                eps[(wr * 16 + quad * 4 + r) * 132 + wc * 64 + nt * 16 + l15] =
                    acc[p][nt][r] + bvl[nt];
        __syncthreads();
        const int grow = row0 + (lr >> 4) * 64 + p * 16 + (lr & 15);
        const int t = grow & (SEQ - 1);
        const int bb = grow >> 11;
        float vals[16];
        #pragma unroll
        for (int q4 = 0; q4 < 4; ++q4) {
            f32x4 vv = *(const f32x4*)&eps[lr * 132 + c0 + q4 * 4];
            vals[q4 * 4 + 0] = vv[0]; vals[q4 * 4 + 1] = vv[1];
            vals[q4 * 4 + 2] = vv[2]; vals[q4 * 4 + 3] = vv[3];
        }
        bf16x8 o0, o1;
        if (rope) {
            const int pbase = t * 32 + (dbase >> 1);
            const float4 cs0 = *(const float4*)&cosT[pbase];
            const float4 cs1 = *(const float4*)&cosT[pbase + 4];
            const float4 sn0 = *(const float4*)&sinT[pbase];
            const float4 sn1 = *(const float4*)&sinT[pbase + 4];
            const float cc[8] = {cs0.x, cs0.y, cs0.z, cs0.w, cs1.x, cs1.y, cs1.z, cs1.w};
            const float ss[8] = {sn0.x, sn0.y, sn0.z, sn0.w, sn1.x, sn1.y, sn1.z, sn1.w};
            #pragma unroll
            for (int i = 0; i < 8; ++i) {
                const float e = vals[2 * i], o = vals[2 * i + 1];
                const float oe = e * cc[i] - o * ss[i];
                const float oo = e * ss[i] + o * cc[i];
                if (i < 4) { o0[2 * i] = (bf16_t)oe; o0[2 * i + 1] = (bf16_t)oo; }
                else { o1[2 * (i - 4)] = (bf16_t)oe; o1[2 * (i - 4) + 1] = (bf16_t)oo; }
            }
        } else {
            #pragma unroll
            for (int i = 0; i < 8; ++i) o0[i] = (bf16_t)vals[i];
            #pragma unroll
            for (int i = 0; i < 8; ++i) o1[i] = (bf16_t)vals[8 + i];
        }
        bf16_t* dst = outp + (((size_t)bb * NH + h) * SEQ + t) * HD + dbase;
        *(bf16x8*)dst = o0;
        *(bf16x8*)(dst + 8) = o1;
    }
}

// ---------------- output GEMM (fp32 out, XCD-swizzled, coalesced epilogue) ------------
__global__ __launch_bounds__(256, 6) void gemm_o(const bf16_t* __restrict__ A,
                                                 const bf16_t* __restrict__ Bt,
                                                 const float* __restrict__ bias,
                                                 float* __restrict__ out) {
    __shared__ __align__(16) unsigned char smem[32 * 132 * 4];
    bf16_t* As = (bf16_t*)smem;
    bf16_t* Bs = (bf16_t*)(smem + 8192);
    float* eps = (float*)smem;
    const int tid = threadIdx.x;
    const int w = tid >> 6;
    const int lane = tid & 63;
    const int l15 = lane & 15;
    const int quad = lane >> 4;
    const int wr = w >> 1, wc = w & 1;
    const int raw = blockIdx.y * 8 + blockIdx.x;
    const int row0 = (raw & 63) * 128, col0 = (raw >> 6) * 128;
    GEMM_KLOOP(A, Bt)
    float bvl[4];
    #pragma unroll
    for (int nt = 0; nt < 4; ++nt) bvl[nt] = bias[col0 + wc * 64 + nt * 16 + l15];
    const int lr = tid >> 3;
    const int cg = tid & 7;
    #pragma unroll
    for (int p = 0; p < 4; ++p) {
        __syncthreads();
        #pragma unroll
        for (int nt = 0; nt < 4; ++nt)
            #pragma unroll
            for (int r = 0; r < 4; ++r)
                eps[(wr * 16 + quad * 4 + r) * 132 + wc * 64 + nt * 16 + l15] =
                    acc[p][nt][r] + bvl[nt];
        __syncthreads();
        const int grow = row0 + (lr >> 4) * 64 + p * 16 + (lr & 15);
        float* dst = out + (size_t)grow * DIMC + col0 + cg * 16;
        #pragma unroll
        for (int q4 = 0; q4 < 4; ++q4) {
            f32x4 vv = *(const f32x4*)&eps[lr * 132 + cg * 16 + q4 * 4];
            *(f32x4*)(dst + q4 * 4) = vv;
        }
    }
}

// ---------------- flash attention (causal, no-max softmax, S^T trick) -----------------
// Grid: 1024 blocks, one 128-row Q-tile each. Schedule: n -> r=n>>8, c=n&255,
// bh=c&63, base=c>>6, j = {base, 7-base, 8+base, 15-base}[r]: each CU's 4
// resident blocks have j summing to 30 (balanced); bh fastest -> XCD locality.
__global__ __launch_bounds__(256, 4) void attn_kernel(const bf16_t* __restrict__ Qr,
                                                      const bf16_t* __restrict__ Kr,
                                                      const bf16_t* __restrict__ Vr,
                                                      bf16_t* __restrict__ O) {
    __shared__ bf16_t Ks[64 * 64];     // swizzled [s][d]
    __shared__ bf16_t Vt[64 * 72];     // [d][s], stride 72
    __shared__ bf16_t Ps[4][32 * 72];  // per-wave [t-local][s], stride 72
    const int tid = threadIdx.x;
    const int w = tid >> 6;
    const int lane = tid & 63;
    const int l15 = lane & 15;
    const int quad = lane >> 4;
    const int n = blockIdx.x;
    const int rnd = n >> 8;
    const int c255 = n & 255;
    const int bh = c255 & 63;
    const int base = c255 >> 6;
    const int j = (rnd == 0) ? base : (rnd == 1) ? (7 - base) : (rnd == 2) ? (8 + base) : (15 - base);
    const int b = bh >> 4, h = bh & 15;
    const bf16_t* Qb = Qr + (size_t)bh * SEQ * HD;
    const bf16_t* Kb = Kr + (size_t)bh * SEQ * HD;
    const bf16_t* Vb = Vr + (size_t)bh * SEQ * HD;
    const float S2 = 0.18033688011112043f;  // 0.125 * log2(e)

    bf16x8 ones;
    #pragma unroll
    for (int j8 = 0; j8 < 8; ++j8) ones[j8] = (bf16_t)1.0f;
    // identity B-fragments for in-register V transpose: B[k][n] = (k == ch*16 + n)
    bf16x8 idB[2];
    #pragma unroll
    for (int ch = 0; ch < 2; ++ch)
        #pragma unroll
        for (int j8 = 0; j8 < 8; ++j8)
            idB[ch][j8] = (quad * 8 + j8 == ch * 16 + l15) ? (bf16_t)1.0f : (bf16_t)0.0f;

    // K async staging lane constants (chunk = 8 s-rows x 64 d)
    const int sIn = lane >> 3;              // s within chunk
    const int gK = ((lane & 7) ^ sIn) * 8;  // swizzled source d-offset
    const int fK = (l15 & 7);               // read-side swizzle key

    const int q0 = j * 128;
    // Q fragments (B-operand): Q[t = q0+mg*64+w*16+l15][d = kc*32+quad*8..]
    bf16x8 qa[2][2];
    #pragma unroll
    for (int mg = 0; mg < 2; ++mg)
        #pragma unroll
        for (int kc = 0; kc < 2; ++kc)
            qa[mg][kc] = *(const bf16x8*)(Qb + (size_t)(q0 + mg * 64 + w * 16 + l15) * HD +
                                          kc * 32 + quad * 8);
    f32x4 acco[2][4] = {};
    f32x4 accl[2] = {};
    const int nIter = 2 * j + 2;
    for (int it = 0; it < nIter; ++it) {
        const int s0 = it * 64;
        __syncthreads();  // B1: all prior-iter LDS reads done
        // K -> Ks via swizzled async copies (2 chunks per wave)
        #pragma unroll
        for (int ci = 0; ci < 2; ++ci) {
            const int c = 2 * w + ci;
            async_copy16(&Ks[c * 512], Kb + (size_t)(s0 + c * 8 + sIn) * HD + gK);
        }
        // V A-fragments direct from global; transpose via identity MFMA -> Vt
        {
            const bf16_t* vsrc = Vb + (size_t)(s0 + w * 16 + l15) * HD + quad * 8;
            bf16x8 av0 = *(const bf16x8*)(vsrc);
            bf16x8 av1 = *(const bf16x8*)(vsrc + 32);
            #pragma unroll
            for (int c = 0; c < 4; ++c) {
                f32x4 zz = {};
                f32x4 tv = MFMA16((c < 2) ? av0 : av1, idB[c & 1], zz);
                bf16x4 pk;
                #pragma unroll
                for (int r = 0; r < 4; ++r) pk[r] = (bf16_t)tv[r];
                *(bf16x4*)&Vt[(c * 16 + l15) * 72 + w * 16 + quad * 4] = pk;
            }
        }
        __syncthreads();  // B2: Ks (async) + Vt visible
        // K fragments (A-operand): K[s = mt*16+l15][d], swizzled address
        bf16x8 kb[4][2];
        #pragma unroll
        for (int mt = 0; mt < 4; ++mt)
            #pragma unroll
            for (int kc = 0; kc < 2; ++kc)
                kb[mt][kc] = *(const bf16x8*)&Ks[(mt * 16 + l15) * 64 +
                                                 (((kc * 4 + quad) ^ fK) << 3)];
        // S^T = K Q^T ; exp -> Ps (b64 s-runs)
        #pragma unroll
        for (int mg = 0; mg < 2; ++mg) {
            if (mg == 0 && it == 2 * j + 1) continue;  // fully-masked
            const bool diag = (it == 2 * j + mg);
            #pragma unroll
            for (int mt = 0; mt < 4; ++mt) {
                bf16x4 pk;
                if (diag && mt > w) {  // fully-masked s-block: skip MFMA+exp
                    #pragma unroll
                    for (int r = 0; r < 4; ++r) pk[r] = (bf16_t)0.0f;
                } else {
                    f32x4 z = {};
                    z = MFMA16(kb[mt][0], qa[mg][0], z);
                    z = MFMA16(kb[mt][1], qa[mg][1], z);
                    #pragma unroll
                    for (int r = 0; r < 4; ++r) {
                        float v = z[r];
                        if (diag && (mt * 16 + quad * 4 + r > w * 16 + l15)) v = -INFINITY;
                        pk[r] = (bf16_t)fast_exp2(S2 * v);
                    }
                }
                *(bf16x4*)&Ps[w][(mg * 16 + l15) * 72 + mt * 16 + quad * 4] = pk;
            }
        }
        asm volatile("s_waitcnt lgkmcnt(0)" ::: "memory");
        // V^T fragments (B-operand) from Vt
        bf16x8 vb[4][2];
        #pragma unroll
        for (int dt = 0; dt < 4; ++dt)
            #pragma unroll
            for (int kc = 0; kc < 2; ++kc)
                vb[dt][kc] = *(const bf16x8*)&Vt[(dt * 16 + l15) * 72 + kc * 32 + quad * 8];
        #pragma unroll
        for (int mg = 0; mg < 2; ++mg) {
            if (mg == 0 && it == 2 * j + 1) continue;
            const bf16x8 pa0 = *(const bf16x8*)&Ps[w][(mg * 16 + l15) * 72 + quad * 8];
            const bf16x8 pa1 = *(const bf16x8*)&Ps[w][(mg * 16 + l15) * 72 + 32 + quad * 8];
            #pragma unroll
            for (int dt = 0; dt < 4; ++dt) {
                acco[mg][dt] = MFMA16(pa0, vb[dt][0], acco[mg][dt]);
                acco[mg][dt] = MFMA16(pa1, vb[dt][1], acco[mg][dt]);
            }
            accl[mg] = MFMA16(pa0, ones, accl[mg]);
            accl[mg] = MFMA16(pa1, ones, accl[mg]);
        }
    }
    // epilogue: O[t][d], t = q0+mg*64+w*16+quad*4+r, d = dt*16+l15
    #pragma unroll
    for (int mg = 0; mg < 2; ++mg) {
        #pragma unroll
        for (int r = 0; r < 4; ++r) {
            const float inv = 1.0f / accl[mg][r];
            const int trow = q0 + mg * 64 + w * 16 + quad * 4 + r;
            bf16_t* orow = O + ((size_t)(b * SEQ + trow)) * DIMC + h * HD;
            #pragma unroll
            for (int dt = 0; dt < 4; ++dt)
                orow[dt * 16 + l15] = (bf16_t)(acco[mg][dt][r] * inv);
        }
    }
}

extern "C" void kernel_launch(void* const* d_in, const int* in_sizes, int n_in,
                              void* d_out, int out_size, void* d_ws, size_t ws_size,
                              hipStream_t stream) {
    const float* query = (const float*)d_in[0];
    const float* key = (const float*)d_in[1];
    const float* value = (const float*)d_in[2];
    const float* Wq = (const float*)d_in[3];
    const float* bq = (const float*)d_in[4];
    const float* Wk = (const float*)d_in[5];
    const float* bk = (const float*)d_in[6];
    const float* Wv = (const float*)d_in[7];
    const float* bv = (const float*)d_in[8];
    const float* Wo = (const float*)d_in[9];
    const float* bo = (const float*)d_in[10];

    char* ws = (char*)d_ws;
    const size_t WT_BYTES = (size_t)DIMC * DIMC * sizeof(bf16_t);          // 2 MB
    const size_t ACT_BYTES = (size_t)BATCH * SEQ * DIMC * sizeof(bf16_t);  // 16 MB
    bf16_t* WT = (bf16_t*)ws;  // WqT,WkT,WvT,WoT consecutive (8 MB)
    bf16_t* WoT = WT + 3 * (size_t)DIMC * DIMC;
    float* cosT = (float*)(ws + 4 * WT_BYTES);
    float* sinT = (float*)(ws + 4 * WT_BYTES + 262144);
    bf16_t* Cb = (bf16_t*)(ws + 4 * WT_BYTES + 2 * 262144);  // 3x16 MB bf16 inputs
    bf16_t* Qr = (bf16_t*)((char*)Cb + 3 * ACT_BYTES);
    bf16_t* Kr = (bf16_t*)((char*)Cb + 4 * ACT_BYTES);
    bf16_t* Vr = (bf16_t*)((char*)Cb + 5 * ACT_BYTES);
    bf16_t* Ob = Cb;  // attention output aliases Cq (free after QKV GEMMs)

    prep<<<dim3(16640), 256, 0, stream>>>(Wq, Wk, Wv, Wo, query, key, value,
                                          WT, cosT, sinT, Cb);
    gemm_qkv<<<dim3(DIMC / 128, (BATCH * SEQ) / 128, 3), 256, 0, stream>>>(
        Cb, WT, bq, bk, bv, Qr, Kr, Vr, cosT, sinT);
    attn_kernel<<<dim3(1024), 256, 0, stream>>>(Qr, Kr, Vr, Ob);
    gemm_o<<<dim3(DIMC / 128, (BATCH * SEQ) / 128), 256, 0, stream>>>(Ob, WoT, bo, (float*)d_out);
}